// Round 13
// baseline (291.164 us; speedup 1.0000x reference)
//
#include <hip/hip_runtime.h>

// CIN (xDeepFM) fused kernel for MI355X (gfx950), round 13.
// Ledger finding: VGPR=64 <=> 2-block co-residency (occ ~40%, 86us r7/r10);
// VGPR>64 <=> 1 block resident (occ ~20%, 95-120us r8/r11/r12). This round
// doubles TLP at constant per-CU work: 1024-thr blocks, 2 families x 8 waves
// (each family = r7's microstructure on ONE batch / 32 cols), grid 512,
// 2 blocks/CU -> 32 waves/CU (8/SIMD), VGPR hard-capped 64 via
// __launch_bounds__(1024, 8). Families read identical weight addresses
// (L1$ coalesces, r10-verified). L1: rt<4 x kh<2 per family, f32 red exchange.

typedef _Float16 f16x8 __attribute__((ext_vector_type(8)));
typedef float f32x4 __attribute__((ext_vector_type(4)));

#define NB 2
#define NBLK 512
#define THREADS 1024
#define K0P 52   // padded L0 steps (s=50,51 zero) for 4-deep prefetch overrun
#define M1P 42   // padded L1 m (m>=39 zero) for 2-deep overrun

__global__ __launch_bounds__(256) void prep_kernel(
    const float* __restrict__ w0, const float* __restrict__ w1,
    _Float16* __restrict__ w0c, _Float16* __restrict__ w1c) {
  int stride = gridDim.x * blockDim.x;
  int tid = blockIdx.x * blockDim.x + threadIdx.x;
  // w0c: [s<52][w8<8][mt<2][l15<16][lhi<4][j<8]; row o=w8*32+mt*16+l15,
  // k-index ip = s*32+lhi*8+j with reorder i' = m*40+n (n<39 valid, else 0).
  const int n0 = K0P * 8192;
  for (int idx = tid; idx < n0; idx += stride) {
    int j = idx & 7, lhi = (idx >> 3) & 3, l15 = (idx >> 5) & 15;
    int mt = (idx >> 9) & 1, w8 = (idx >> 10) & 7, s = idx >> 13;
    int o = w8 * 32 + mt * 16 + l15;
    int ip = s * 32 + lhi * 8 + j;
    float v = 0.f;
    if (ip < 1560) {
      unsigned m = (unsigned)ip / 40u;
      unsigned n = (unsigned)ip - m * 40u;
      if (n < 39u) v = w0[o * 1521 + m * 39 + n];
    }
    w0c[idx] = (_Float16)v;
  }
  // w1c: [m<42][kh<2][rt<4][kf<2][mt<2][l15<16][lhi<4][j<8];
  //      row o=rt*32+mt*16+l15, k = kh*64+kf*32+lhi*8+j (within W1_m).
  const int n1 = M1P * 16384;
  for (int idx = tid; idx < n1; idx += stride) {
    int j = idx & 7, lhi = (idx >> 3) & 3, l15 = (idx >> 5) & 15;
    int mt = (idx >> 9) & 1, kf = (idx >> 10) & 1, rt = (idx >> 11) & 3;
    int kh = (idx >> 13) & 1, m = idx >> 14;
    int o = rt * 32 + mt * 16 + l15;
    int k = kh * 64 + kf * 32 + lhi * 8 + j;
    float v = (m < 39) ? w1[o * 4992 + m * 128 + k] : 0.f;
    w1c[idx] = (_Float16)v;
  }
}

__global__ __launch_bounds__(1024, 8) void cin_kernel(
    const float* __restrict__ x,
    const _Float16* __restrict__ w0c, const float* __restrict__ b0,
    const _Float16* __restrict__ w1c, const float* __restrict__ b1,
    float* __restrict__ out) {
  // LDS: 5120 + 17408 + 34816 = 57344 B -> 2 blocks/CU (114688 <= 160K)
  __shared__ __align__(16) _Float16 xs[NB * 32 * 40];   // [c=(b,d)][40] (slot 39 = 0)
  __shared__ __align__(16) _Float16 h1[NB * 32 * 136];  // [fam c][136] h1a
  __shared__ __align__(16) float red[8 * 32 * 34];      // [fam*4+rt][row][col] exchange

  const int t = threadIdx.x;
  const int bb = blockIdx.x * NB;
  const int w = t >> 6;          // wave 0..15
  const int fam = w >> 3;        // family = batch index within block
  const int w8 = w & 7;          // wave within family
  const int l15 = t & 15;
  const int lhi = (t >> 4) & 3;
  const int lane_off = ((l15 << 2) | lhi) << 3;

  int xrow[2];
#pragma unroll
  for (int nt = 0; nt < 2; ++nt) xrow[nt] = (fam * 32 + nt * 16 + l15) * 40;

  // ---- stage x -> xs[c][m], f16 ----
  for (int idx = t; idx < NB * 39 * 32; idx += THREADS) {
    int b = idx / 1248; int rem = idx - b * 1248;
    int m = rem >> 5; int d = rem & 31;
    xs[(b * 32 + d) * 40 + m] = (_Float16)x[(bb + b) * 1248 + rem];
  }
  if (t < NB * 32) xs[t * 40 + 39] = (_Float16)0.f;  // zero pad slot 39
  __syncthreads();

  // ============ LAYER 0 (r7 microstructure, 32 rows x 32 cols/wave) ============
  f32x4 acc[2][2] = {};
  const _Float16* p0 = w0c + w8 * 1024 + lane_off;

  auto loadA0 = [&](int s, f16x8 (&af)[2]) {
    const _Float16* p = p0 + s * 8192;
    af[0] = *(const f16x8*)(p);
    af[1] = *(const f16x8*)(p + 512);
  };
  auto zfr = [&](int s, f16x8 (&bz)[2]) {
    unsigned i0 = (unsigned)(s * 32) + (unsigned)lhi * 8u;
    unsigned m = (i0 * 52429u) >> 21;   // i0/40 (exact for i0 < 2^16)
    unsigned nb = i0 - m * 40u;
#pragma unroll
    for (int nt = 0; nt < 2; ++nt) {
      _Float16 xm = xs[xrow[nt] + m];                 // m==39 -> 0
      f16x8 xn = *(const f16x8*)&xs[xrow[nt] + nb];   // 16B-aligned (80B rows)
      bz[nt] = xn * xm;                               // v_pk_mul_f16
    }
  };
  auto comp0 = [&](f16x8 (&af)[2], f16x8 (&bz)[2]) {
#pragma unroll
    for (int mt = 0; mt < 2; ++mt)
#pragma unroll
      for (int nt = 0; nt < 2; ++nt)
        acc[mt][nt] = __builtin_amdgcn_mfma_f32_16x16x32_f16(af[mt], bz[nt], acc[mt][nt], 0, 0, 0);
  };

  {
    f16x8 af0[2], af1[2], af2[2], af3[2];
    loadA0(0, af0); loadA0(1, af1); loadA0(2, af2); loadA0(3, af3);
    for (int s = 0; s < 48; s += 4) {
      f16x8 bz[2];
      zfr(s + 0, bz); comp0(af0, bz); loadA0(s + 4, af0);
      zfr(s + 1, bz); comp0(af1, bz); loadA0(s + 5, af1);
      zfr(s + 2, bz); comp0(af2, bz); loadA0(s + 6, af2);
      zfr(s + 3, bz); comp0(af3, bz); loadA0(s + 7, af3);   // max 51 < K0P
    }
    f16x8 bz[2];
    zfr(48, bz); comp0(af0, bz);
    zfr(49, bz); comp0(af1, bz);
  }

  // ---- epilogue 0: bias+relu; o<128 -> h1; o>=128 -> d-sum -> out[ch 0..127] ----
  if (w8 < 4) {
#pragma unroll
    for (int mt = 0; mt < 2; ++mt)
#pragma unroll
      for (int nt = 0; nt < 2; ++nt) {
        int c = fam * 32 + nt * 16 + l15;
#pragma unroll
        for (int r = 0; r < 4; ++r) {
          int o = w8 * 32 + mt * 16 + lhi * 4 + r;
          float v = fmaxf(acc[mt][nt][r] + b0[o], 0.f);
          h1[c * 136 + o] = (_Float16)v;
        }
      }
  } else {
#pragma unroll
    for (int mt = 0; mt < 2; ++mt)
#pragma unroll
      for (int r = 0; r < 4; ++r) {
        int o = w8 * 32 + mt * 16 + lhi * 4 + r;  // 128..255
        float bias = b0[o];
        float v = fmaxf(acc[mt][0][r] + bias, 0.f) + fmaxf(acc[mt][1][r] + bias, 0.f);
        v += __shfl_xor(v, 1); v += __shfl_xor(v, 2);
        v += __shfl_xor(v, 4); v += __shfl_xor(v, 8);
        if (l15 == 0) out[(bb + fam) * 256 + (o - 128)] = v;
      }
  }
  __syncthreads();  // h1 visible

  // ============ LAYER 1 (per family: 4 row-groups x 2 K-halves) ============
  const int rt = w8 >> 1;   // rows rt*32 .. rt*32+31
  const int kh = w8 & 1;    // k in [kh*64, kh*64+64)

  f16x8 hf[2][2];           // [kf][nt] persistent B frags (16 VGPR)
#pragma unroll
  for (int kf = 0; kf < 2; ++kf)
#pragma unroll
    for (int nt = 0; nt < 2; ++nt)
      hf[kf][nt] = *(const f16x8*)&h1[(fam * 32 + nt * 16 + l15) * 136 + kh * 64 + kf * 32 + lhi * 8];

  f32x4 acc2[2][2] = {};
  const _Float16* p1 = w1c + (kh * 4 + rt) * 2048 + lane_off;

  auto loadA1 = [&](int m, f16x8 (&wf)[2][2]) {  // [kf][mt]
    const _Float16* p = p1 + m * 16384;
    wf[0][0] = *(const f16x8*)(p);
    wf[0][1] = *(const f16x8*)(p + 512);
    wf[1][0] = *(const f16x8*)(p + 1024);
    wf[1][1] = *(const f16x8*)(p + 1536);
  };
  auto computeM = [&](int m, f16x8 (&wf)[2][2]) {
    float xmv[2];
#pragma unroll
    for (int nt = 0; nt < 2; ++nt) xmv[nt] = (float)xs[xrow[nt] + m];
#pragma unroll
    for (int mt = 0; mt < 2; ++mt)
#pragma unroll
      for (int nt = 0; nt < 2; ++nt) {
        f32x4 Y = __builtin_amdgcn_mfma_f32_16x16x32_f16(wf[0][mt], hf[0][nt],
                                                         (f32x4){0.f, 0.f, 0.f, 0.f}, 0, 0, 0);
        Y = __builtin_amdgcn_mfma_f32_16x16x32_f16(wf[1][mt], hf[1][nt], Y, 0, 0, 0);
        acc2[mt][nt] += Y * xmv[nt];   // v_pk_fma_f32
      }
  };

  {
    f16x8 wfA[2][2], wfB[2][2];
    loadA1(0, wfA);
    loadA1(1, wfB);
    for (int m = 0; m < 40; m += 2) {     // m=39 contributes 0 (zero pad both sides)
      computeM(m, wfA);     loadA1(m + 2, wfA);   // max 41 < M1P
      computeM(m + 1, wfB); loadA1(m + 3, wfB);
    }
  }

  // ---- combine K-halves via LDS: kh==1 writes, kh==0 adds + epilogue ----
  __syncthreads();
  if (kh == 1) {
#pragma unroll
    for (int mt = 0; mt < 2; ++mt)
#pragma unroll
      for (int nt = 0; nt < 2; ++nt)
#pragma unroll
        for (int r = 0; r < 4; ++r) {
          int row = mt * 16 + lhi * 4 + r, c = nt * 16 + l15;
          red[(fam * 4 + rt) * 1088 + row * 34 + c] = acc2[mt][nt][r];
        }
  }
  __syncthreads();
  if (kh == 0) {
#pragma unroll
    for (int mt = 0; mt < 2; ++mt) {
#pragma unroll
      for (int r = 0; r < 4; ++r) {
        int o = rt * 32 + mt * 16 + lhi * 4 + r;  // 0..127
        float bias = b1[o];
        int row = mt * 16 + lhi * 4 + r;
        float v = 0.f;
#pragma unroll
        for (int nt = 0; nt < 2; ++nt) {
          float tot = acc2[mt][nt][r] + red[(fam * 4 + rt) * 1088 + row * 34 + nt * 16 + l15];
          v += fmaxf(tot + bias, 0.f);
        }
        v += __shfl_xor(v, 1); v += __shfl_xor(v, 2);
        v += __shfl_xor(v, 4); v += __shfl_xor(v, 8);
        if (l15 == 0) out[(bb + fam) * 256 + 128 + o] = v;
      }
    }
  }
}

extern "C" void kernel_launch(void* const* d_in, const int* in_sizes, int n_in,
                              void* d_out, int out_size, void* d_ws, size_t ws_size,
                              hipStream_t stream) {
  const float* x  = (const float*)d_in[0];
  const float* w0 = (const float*)d_in[1];
  const float* b0 = (const float*)d_in[2];
  const float* w1 = (const float*)d_in[3];
  const float* b1 = (const float*)d_in[4];
  float* out = (float*)d_out;

  _Float16* w0c = (_Float16*)d_ws;             // 52*8192  f16 = 851968 B
  _Float16* w1c = w0c + K0P * 8192;            // 42*16384 f16 = 1376256 B

  prep_kernel<<<256, 256, 0, stream>>>(w0, w1, w0c, w1c);
  cin_kernel<<<NBLK, THREADS, 0, stream>>>(x, w0c, b0, w1c, b1, out);
}

// Round 14
// 139.033 us; speedup vs baseline: 2.0942x; 2.0942x over previous
//
#include <hip/hip_runtime.h>

// CIN (xDeepFM) fused kernel for MI355X (gfx950), round 14.
// = round 13 with the launch bound CORRECTED: empirically (r4/r5/r10/r13) the
// 2nd __launch_bounds__ arg acts as BLOCKS/CU on this hipcc. (1024,8) forced a
// 32-VGPR cap -> catastrophic spill (409MB scratch, 305us). (1024,2) targets
// 2 blocks/CU x 16 waves = 32 waves/CU (8/SIMD), VGPR cap 64 — the TLP
// experiment r13 was meant to run. Everything else byte-identical to r13.

typedef _Float16 f16x8 __attribute__((ext_vector_type(8)));
typedef float f32x4 __attribute__((ext_vector_type(4)));

#define NB 2
#define NBLK 512
#define THREADS 1024
#define K0P 52   // padded L0 steps (s=50,51 zero) for 4-deep prefetch overrun
#define M1P 42   // padded L1 m (m>=39 zero) for 2-deep overrun

__global__ __launch_bounds__(256) void prep_kernel(
    const float* __restrict__ w0, const float* __restrict__ w1,
    _Float16* __restrict__ w0c, _Float16* __restrict__ w1c) {
  int stride = gridDim.x * blockDim.x;
  int tid = blockIdx.x * blockDim.x + threadIdx.x;
  // w0c: [s<52][w8<8][mt<2][l15<16][lhi<4][j<8]; row o=w8*32+mt*16+l15,
  // k-index ip = s*32+lhi*8+j with reorder i' = m*40+n (n<39 valid, else 0).
  const int n0 = K0P * 8192;
  for (int idx = tid; idx < n0; idx += stride) {
    int j = idx & 7, lhi = (idx >> 3) & 3, l15 = (idx >> 5) & 15;
    int mt = (idx >> 9) & 1, w8 = (idx >> 10) & 7, s = idx >> 13;
    int o = w8 * 32 + mt * 16 + l15;
    int ip = s * 32 + lhi * 8 + j;
    float v = 0.f;
    if (ip < 1560) {
      unsigned m = (unsigned)ip / 40u;
      unsigned n = (unsigned)ip - m * 40u;
      if (n < 39u) v = w0[o * 1521 + m * 39 + n];
    }
    w0c[idx] = (_Float16)v;
  }
  // w1c: [m<42][kh<2][rt<4][kf<2][mt<2][l15<16][lhi<4][j<8];
  //      row o=rt*32+mt*16+l15, k = kh*64+kf*32+lhi*8+j (within W1_m).
  const int n1 = M1P * 16384;
  for (int idx = tid; idx < n1; idx += stride) {
    int j = idx & 7, lhi = (idx >> 3) & 3, l15 = (idx >> 5) & 15;
    int mt = (idx >> 9) & 1, kf = (idx >> 10) & 1, rt = (idx >> 11) & 3;
    int kh = (idx >> 13) & 1, m = idx >> 14;
    int o = rt * 32 + mt * 16 + l15;
    int k = kh * 64 + kf * 32 + lhi * 8 + j;
    float v = (m < 39) ? w1[o * 4992 + m * 128 + k] : 0.f;
    w1c[idx] = (_Float16)v;
  }
}

__global__ __launch_bounds__(1024, 2) void cin_kernel(
    const float* __restrict__ x,
    const _Float16* __restrict__ w0c, const float* __restrict__ b0,
    const _Float16* __restrict__ w1c, const float* __restrict__ b1,
    float* __restrict__ out) {
  // LDS: 5120 + 17408 + 34816 = 57344 B -> 2 blocks/CU (114688 <= 160K)
  __shared__ __align__(16) _Float16 xs[NB * 32 * 40];   // [c=(b,d)][40] (slot 39 = 0)
  __shared__ __align__(16) _Float16 h1[NB * 32 * 136];  // [fam c][136] h1a
  __shared__ __align__(16) float red[8 * 32 * 34];      // [fam*4+rt][row][col] exchange

  const int t = threadIdx.x;
  const int bb = blockIdx.x * NB;
  const int w = t >> 6;          // wave 0..15
  const int fam = w >> 3;        // family = batch index within block
  const int w8 = w & 7;          // wave within family
  const int l15 = t & 15;
  const int lhi = (t >> 4) & 3;
  const int lane_off = ((l15 << 2) | lhi) << 3;

  int xrow[2];
#pragma unroll
  for (int nt = 0; nt < 2; ++nt) xrow[nt] = (fam * 32 + nt * 16 + l15) * 40;

  // ---- stage x -> xs[c][m], f16 ----
  for (int idx = t; idx < NB * 39 * 32; idx += THREADS) {
    int b = idx / 1248; int rem = idx - b * 1248;
    int m = rem >> 5; int d = rem & 31;
    xs[(b * 32 + d) * 40 + m] = (_Float16)x[(bb + b) * 1248 + rem];
  }
  if (t < NB * 32) xs[t * 40 + 39] = (_Float16)0.f;  // zero pad slot 39
  __syncthreads();

  // ============ LAYER 0 (r7 microstructure, 32 rows x 32 cols/wave) ============
  f32x4 acc[2][2] = {};
  const _Float16* p0 = w0c + w8 * 1024 + lane_off;

  auto loadA0 = [&](int s, f16x8 (&af)[2]) {
    const _Float16* p = p0 + s * 8192;
    af[0] = *(const f16x8*)(p);
    af[1] = *(const f16x8*)(p + 512);
  };
  auto zfr = [&](int s, f16x8 (&bz)[2]) {
    unsigned i0 = (unsigned)(s * 32) + (unsigned)lhi * 8u;
    unsigned m = (i0 * 52429u) >> 21;   // i0/40 (exact for i0 < 2^16)
    unsigned nb = i0 - m * 40u;
#pragma unroll
    for (int nt = 0; nt < 2; ++nt) {
      _Float16 xm = xs[xrow[nt] + m];                 // m==39 -> 0
      f16x8 xn = *(const f16x8*)&xs[xrow[nt] + nb];   // 16B-aligned (80B rows)
      bz[nt] = xn * xm;                               // v_pk_mul_f16
    }
  };
  auto comp0 = [&](f16x8 (&af)[2], f16x8 (&bz)[2]) {
#pragma unroll
    for (int mt = 0; mt < 2; ++mt)
#pragma unroll
      for (int nt = 0; nt < 2; ++nt)
        acc[mt][nt] = __builtin_amdgcn_mfma_f32_16x16x32_f16(af[mt], bz[nt], acc[mt][nt], 0, 0, 0);
  };

  {
    f16x8 af0[2], af1[2], af2[2], af3[2];
    loadA0(0, af0); loadA0(1, af1); loadA0(2, af2); loadA0(3, af3);
    for (int s = 0; s < 48; s += 4) {
      f16x8 bz[2];
      zfr(s + 0, bz); comp0(af0, bz); loadA0(s + 4, af0);
      zfr(s + 1, bz); comp0(af1, bz); loadA0(s + 5, af1);
      zfr(s + 2, bz); comp0(af2, bz); loadA0(s + 6, af2);
      zfr(s + 3, bz); comp0(af3, bz); loadA0(s + 7, af3);   // max 51 < K0P
    }
    f16x8 bz[2];
    zfr(48, bz); comp0(af0, bz);
    zfr(49, bz); comp0(af1, bz);
  }

  // ---- epilogue 0: bias+relu; o<128 -> h1; o>=128 -> d-sum -> out[ch 0..127] ----
  if (w8 < 4) {
#pragma unroll
    for (int mt = 0; mt < 2; ++mt)
#pragma unroll
      for (int nt = 0; nt < 2; ++nt) {
        int c = fam * 32 + nt * 16 + l15;
#pragma unroll
        for (int r = 0; r < 4; ++r) {
          int o = w8 * 32 + mt * 16 + lhi * 4 + r;
          float v = fmaxf(acc[mt][nt][r] + b0[o], 0.f);
          h1[c * 136 + o] = (_Float16)v;
        }
      }
  } else {
#pragma unroll
    for (int mt = 0; mt < 2; ++mt)
#pragma unroll
      for (int r = 0; r < 4; ++r) {
        int o = w8 * 32 + mt * 16 + lhi * 4 + r;  // 128..255
        float bias = b0[o];
        float v = fmaxf(acc[mt][0][r] + bias, 0.f) + fmaxf(acc[mt][1][r] + bias, 0.f);
        v += __shfl_xor(v, 1); v += __shfl_xor(v, 2);
        v += __shfl_xor(v, 4); v += __shfl_xor(v, 8);
        if (l15 == 0) out[(bb + fam) * 256 + (o - 128)] = v;
      }
  }
  __syncthreads();  // h1 visible

  // ============ LAYER 1 (per family: 4 row-groups x 2 K-halves) ============
  const int rt = w8 >> 1;   // rows rt*32 .. rt*32+31
  const int kh = w8 & 1;    // k in [kh*64, kh*64+64)

  f16x8 hf[2][2];           // [kf][nt] persistent B frags (16 VGPR)
#pragma unroll
  for (int kf = 0; kf < 2; ++kf)
#pragma unroll
    for (int nt = 0; nt < 2; ++nt)
      hf[kf][nt] = *(const f16x8*)&h1[(fam * 32 + nt * 16 + l15) * 136 + kh * 64 + kf * 32 + lhi * 8];

  f32x4 acc2[2][2] = {};
  const _Float16* p1 = w1c + (kh * 4 + rt) * 2048 + lane_off;

  auto loadA1 = [&](int m, f16x8 (&wf)[2][2]) {  // [kf][mt]
    const _Float16* p = p1 + m * 16384;
    wf[0][0] = *(const f16x8*)(p);
    wf[0][1] = *(const f16x8*)(p + 512);
    wf[1][0] = *(const f16x8*)(p + 1024);
    wf[1][1] = *(const f16x8*)(p + 1536);
  };
  auto computeM = [&](int m, f16x8 (&wf)[2][2]) {
    float xmv[2];
#pragma unroll
    for (int nt = 0; nt < 2; ++nt) xmv[nt] = (float)xs[xrow[nt] + m];
#pragma unroll
    for (int mt = 0; mt < 2; ++mt)
#pragma unroll
      for (int nt = 0; nt < 2; ++nt) {
        f32x4 Y = __builtin_amdgcn_mfma_f32_16x16x32_f16(wf[0][mt], hf[0][nt],
                                                         (f32x4){0.f, 0.f, 0.f, 0.f}, 0, 0, 0);
        Y = __builtin_amdgcn_mfma_f32_16x16x32_f16(wf[1][mt], hf[1][nt], Y, 0, 0, 0);
        acc2[mt][nt] += Y * xmv[nt];   // v_pk_fma_f32
      }
  };

  {
    f16x8 wfA[2][2], wfB[2][2];
    loadA1(0, wfA);
    loadA1(1, wfB);
    for (int m = 0; m < 40; m += 2) {     // m=39 contributes 0 (zero pad both sides)
      computeM(m, wfA);     loadA1(m + 2, wfA);   // max 41 < M1P
      computeM(m + 1, wfB); loadA1(m + 3, wfB);
    }
  }

  // ---- combine K-halves via LDS: kh==1 writes, kh==0 adds + epilogue ----
  __syncthreads();
  if (kh == 1) {
#pragma unroll
    for (int mt = 0; mt < 2; ++mt)
#pragma unroll
      for (int nt = 0; nt < 2; ++nt)
#pragma unroll
        for (int r = 0; r < 4; ++r) {
          int row = mt * 16 + lhi * 4 + r, c = nt * 16 + l15;
          red[(fam * 4 + rt) * 1088 + row * 34 + c] = acc2[mt][nt][r];
        }
  }
  __syncthreads();
  if (kh == 0) {
#pragma unroll
    for (int mt = 0; mt < 2; ++mt) {
#pragma unroll
      for (int r = 0; r < 4; ++r) {
        int o = rt * 32 + mt * 16 + lhi * 4 + r;  // 0..127
        float bias = b1[o];
        int row = mt * 16 + lhi * 4 + r;
        float v = 0.f;
#pragma unroll
        for (int nt = 0; nt < 2; ++nt) {
          float tot = acc2[mt][nt][r] + red[(fam * 4 + rt) * 1088 + row * 34 + nt * 16 + l15];
          v += fmaxf(tot + bias, 0.f);
        }
        v += __shfl_xor(v, 1); v += __shfl_xor(v, 2);
        v += __shfl_xor(v, 4); v += __shfl_xor(v, 8);
        if (l15 == 0) out[(bb + fam) * 256 + 128 + o] = v;
      }
    }
  }
}

extern "C" void kernel_launch(void* const* d_in, const int* in_sizes, int n_in,
                              void* d_out, int out_size, void* d_ws, size_t ws_size,
                              hipStream_t stream) {
  const float* x  = (const float*)d_in[0];
  const float* w0 = (const float*)d_in[1];
  const float* b0 = (const float*)d_in[2];
  const float* w1 = (const float*)d_in[3];
  const float* b1 = (const float*)d_in[4];
  float* out = (float*)d_out;

  _Float16* w0c = (_Float16*)d_ws;             // 52*8192  f16 = 851968 B
  _Float16* w1c = w0c + K0P * 8192;            // 42*16384 f16 = 1376256 B

  prep_kernel<<<256, 256, 0, stream>>>(w0, w1, w0c, w1c);
  cin_kernel<<<NBLK, THREADS, 0, stream>>>(x, w0c, b0, w1c, b1, out);
}

// Round 15
// 89.728 us; speedup vs baseline: 3.2450x; 1.5495x over previous
//
#include <hip/hip_runtime.h>

// CIN (xDeepFM) fused kernel for MI355X (gfx950), round 15.
// = round 7 (86us champion) with L0's z-generation SOFTWARE-PIPELINED:
// zld(s+1) [8 LDS reads -> named regs] issues BEFORE comp0(s)'s 8 MFMAs
// (~155cy), hiding the ~120cy LDS latency that r7 exposed every step.
// zmul(s) [16 v_pk_mul] runs on data loaded one step earlier. Weight ring
// 4->2 (depth shown neutral r5/r6) to offset the raw buffer's VGPRs.
// L1 / epilogues / layouts / grid byte-identical to r7.

typedef _Float16 f16x8 __attribute__((ext_vector_type(8)));
typedef float f32x4 __attribute__((ext_vector_type(4)));

#define NB 2
#define NBLK 512
#define THREADS 512
#define K0P 52   // padded L0 steps (s=50,51 zero weights) for prefetch overrun
#define M1P 42   // padded L1 m (m>=39 zero) for 2-deep overrun

__global__ __launch_bounds__(256) void prep_kernel(
    const float* __restrict__ w0, const float* __restrict__ w1,
    _Float16* __restrict__ w0c, _Float16* __restrict__ w1c) {
  int stride = gridDim.x * blockDim.x;
  int tid = blockIdx.x * blockDim.x + threadIdx.x;
  // w0c: [s<52][w8<8][mt<2][l15<16][lhi<4][j<8]; row o=w8*32+mt*16+l15,
  // k-index ip = s*32+lhi*8+j with reorder i' = m*40+n (n<39 valid, else 0).
  const int n0 = K0P * 8192;
  for (int idx = tid; idx < n0; idx += stride) {
    int j = idx & 7, lhi = (idx >> 3) & 3, l15 = (idx >> 5) & 15;
    int mt = (idx >> 9) & 1, w8 = (idx >> 10) & 7, s = idx >> 13;
    int o = w8 * 32 + mt * 16 + l15;
    int ip = s * 32 + lhi * 8 + j;
    float v = 0.f;
    if (ip < 1560) {
      unsigned m = (unsigned)ip / 40u;
      unsigned n = (unsigned)ip - m * 40u;
      if (n < 39u) v = w0[o * 1521 + m * 39 + n];
    }
    w0c[idx] = (_Float16)v;
  }
  // w1c: [m<42][kh<2][rt<4][kf<2][mt<2][l15<16][lhi<4][j<8];
  //      row o=rt*32+mt*16+l15, k = kh*64+kf*32+lhi*8+j (within W1_m).
  const int n1 = M1P * 16384;
  for (int idx = tid; idx < n1; idx += stride) {
    int j = idx & 7, lhi = (idx >> 3) & 3, l15 = (idx >> 5) & 15;
    int mt = (idx >> 9) & 1, kf = (idx >> 10) & 1, rt = (idx >> 11) & 3;
    int kh = (idx >> 13) & 1, m = idx >> 14;
    int o = rt * 32 + mt * 16 + l15;
    int k = kh * 64 + kf * 32 + lhi * 8 + j;
    float v = (m < 39) ? w1[o * 4992 + m * 128 + k] : 0.f;
    w1c[idx] = (_Float16)v;
  }
}

__global__ __launch_bounds__(512, 2) void cin_kernel(
    const float* __restrict__ x,
    const _Float16* __restrict__ w0c, const float* __restrict__ b0,
    const _Float16* __restrict__ w1c, const float* __restrict__ b1,
    float* __restrict__ out) {
  // LDS: 5120 + 17408 + 33280 = 55808 B -> 2 blocks/CU
  __shared__ __align__(16) _Float16 xs[NB * 32 * 40];    // [c=(b,d)][40] (slot 39 = 0)
  __shared__ __align__(16) _Float16 h1[NB * 32 * 136];   // [c][136] h1a (f16)
  __shared__ __align__(16) float red[4 * 32 * 65];       // K-half exchange, row pad 65

  const int t = threadIdx.x;
  const int bb = blockIdx.x * NB;
  const int w = t >> 6;          // wave id 0..7
  const int l15 = t & 15;
  const int lhi = (t >> 4) & 3;
  const int lane_off = ((l15 << 2) | lhi) << 3;  // element offset in 1KB chunk

  int xrow[4];
#pragma unroll
  for (int nt = 0; nt < 4; ++nt) xrow[nt] = (nt * 16 + l15) * 40;

  // ---- load x[b] -> xs transposed [c][m], f16 ----
  for (int idx = t; idx < NB * 39 * 32; idx += THREADS) {
    int b = idx / 1248; int rem = idx - b * 1248;
    int m = rem >> 5; int d = rem & 31;
    xs[(b * 32 + d) * 40 + m] = (_Float16)x[(bb + b) * 1248 + rem];
  }
  if (t < NB * 32) xs[t * 40 + 39] = (_Float16)0.f;  // zero the m=39 pad
  __syncthreads();

  // ======== LAYER 0 (barrier-free; z-chain software-pipelined 1 step) ========
  f32x4 acc[2][4] = {};
  const _Float16* p0 = w0c + w * 1024 + lane_off;

  auto loadA0 = [&](int s, f16x8 (&af)[2]) {
    const _Float16* p = p0 + s * 8192;
    af[0] = *(const f16x8*)(p);
    af[1] = *(const f16x8*)(p + 512);
  };

  f16x8 xnw[4];        // raw xn vectors (loaded 1 step ahead)
  _Float16 xmw[4];     // raw xm scalars
  auto zld = [&](int s) {
    unsigned i0 = (unsigned)(s * 32) + (unsigned)lhi * 8u;
    unsigned m = (i0 * 52429u) >> 21;   // i0/40 (exact for i0 < 2^16)
    unsigned nb = i0 - m * 40u;
#pragma unroll
    for (int nt = 0; nt < 4; ++nt) {
      xmw[nt] = xs[xrow[nt] + m];                    // m==39 -> 0
      xnw[nt] = *(const f16x8*)&xs[xrow[nt] + nb];   // 16B-aligned (80B rows)
    }
  };
  auto zmul = [&](f16x8 (&bz)[4]) {
#pragma unroll
    for (int nt = 0; nt < 4; ++nt) bz[nt] = xnw[nt] * xmw[nt];   // v_pk_mul_f16
  };
  auto comp0 = [&](f16x8 (&af)[2], f16x8 (&bz)[4]) {
#pragma unroll
    for (int mt = 0; mt < 2; ++mt)
#pragma unroll
      for (int nt = 0; nt < 4; ++nt)
        acc[mt][nt] = __builtin_amdgcn_mfma_f32_16x16x32_f16(af[mt], bz[nt], acc[mt][nt], 0, 0, 0);
  };

  {
    f16x8 afA[2], afB[2];
    loadA0(0, afA); loadA0(1, afB);
    zld(0);
    for (int s = 0; s < 50; s += 2) {
      f16x8 bz[4];
      zmul(bz);                 // step s (data landed during previous MFMAs)
      zld(s + 1);               // issue next step's LDS reads...
      comp0(afA, bz);           // ...hidden under these 8 MFMAs
      loadA0(s + 2, afA);       // max 50 < K0P
      zmul(bz);                 // step s+1
      if (s + 2 < 50) zld(s + 2);
      comp0(afB, bz);
      loadA0(s + 3, afB);       // max 51 < K0P
    }
  }

  // ---- epilogue 0: bias+relu; o<128 -> h1a LDS; o>=128 -> d-sum -> out[ch 0..127]
  if (w < 4) {
#pragma unroll
    for (int mt = 0; mt < 2; ++mt) {
#pragma unroll
      for (int nt = 0; nt < 4; ++nt) {
        int c = nt * 16 + l15;
        int hbase = c * 136;
#pragma unroll
        for (int r = 0; r < 4; ++r) {
          int o = w * 32 + mt * 16 + lhi * 4 + r;
          float v = fmaxf(acc[mt][nt][r] + b0[o], 0.f);
          h1[hbase + o] = (_Float16)v;
        }
      }
    }
  } else {
#pragma unroll
    for (int mt = 0; mt < 2; ++mt) {
#pragma unroll
      for (int r = 0; r < 4; ++r) {
        int o = w * 32 + mt * 16 + lhi * 4 + r;  // 128..255
        float bias = b0[o];
        float sb0 = 0.f, sb1 = 0.f;
#pragma unroll
        for (int nt = 0; nt < 4; ++nt) {
          float v = fmaxf(acc[mt][nt][r] + bias, 0.f);
          v += __shfl_xor(v, 1); v += __shfl_xor(v, 2);
          v += __shfl_xor(v, 4); v += __shfl_xor(v, 8);
          if (nt < 2) sb0 += v; else sb1 += v;
        }
        if (l15 == 0) {
          out[(bb + 0) * 256 + (o - 128)] = sb0;
          out[(bb + 1) * 256 + (o - 128)] = sb1;
        }
      }
    }
  }
  __syncthreads();  // h1a visible to all waves

  // ============ LAYER 1 (r7 verbatim: 4 row-groups x 2 K-halves) ============
  const int rt = w >> 1;   // row group: rows rt*32 .. rt*32+31
  const int kh = w & 1;    // K half: k in [kh*64, kh*64+64)

  // hf[kf][nt]: persistent B fragments of h for this K-half (32 VGPRs)
  f16x8 hf[2][4];
#pragma unroll
  for (int kf = 0; kf < 2; ++kf)
#pragma unroll
    for (int nt = 0; nt < 4; ++nt)
      hf[kf][nt] = *(const f16x8*)&h1[(nt * 16 + l15) * 136 + (kh * 2 + kf) * 32 + lhi * 8];

  f32x4 acc2[2][4] = {};
  const _Float16* p1 = w1c + (kh * 4 + rt) * 2048 + lane_off;

  float xmv[2][4];
  auto xmvld = [&](int m, int b) {
#pragma unroll
    for (int nt = 0; nt < 4; ++nt) xmv[b][nt] = (float)xs[xrow[nt] + m];
  };
  auto loadA1 = [&](int m, f16x8 (&wf)[2][2]) {
    const _Float16* p = p1 + m * 16384;
    wf[0][0] = *(const f16x8*)(p);
    wf[0][1] = *(const f16x8*)(p + 512);
    wf[1][0] = *(const f16x8*)(p + 1024);
    wf[1][1] = *(const f16x8*)(p + 1536);
  };
  auto computeM = [&](f16x8 (&wf)[2][2], float (&xv)[4]) {
#pragma unroll
    for (int mt = 0; mt < 2; ++mt)
#pragma unroll
      for (int nt = 0; nt < 4; ++nt) {
        f32x4 Y = __builtin_amdgcn_mfma_f32_16x16x32_f16(wf[0][mt], hf[0][nt],
                                                         (f32x4){0.f, 0.f, 0.f, 0.f}, 0, 0, 0);
        Y = __builtin_amdgcn_mfma_f32_16x16x32_f16(wf[1][mt], hf[1][nt], Y, 0, 0, 0);
        acc2[mt][nt] += Y * xv[nt];   // v_pk_fma_f32
      }
  };

  {
    f16x8 wfA[2][2], wfB[2][2];
    loadA1(0, wfA);
    loadA1(1, wfB);
    xmvld(0, 0);
    for (int m = 0; m < 40; m += 2) {
      xmvld(m + 1, 1);
      computeM(wfA, xmv[0]);     loadA1(m + 2, wfA);   // max 41 < M1P
      if (m + 2 < 40) xmvld(m + 2, 0);
      computeM(wfB, xmv[1]);     loadA1(m + 3, wfB);
    }
  }

  // ---- combine K-halves via LDS: kh==1 writes, kh==0 adds ----
  __syncthreads();
  if (kh == 1) {
#pragma unroll
    for (int mt = 0; mt < 2; ++mt)
#pragma unroll
      for (int nt = 0; nt < 4; ++nt)
#pragma unroll
        for (int r = 0; r < 4; ++r) {
          int row = mt * 16 + lhi * 4 + r, c = nt * 16 + l15;
          red[(rt * 32 + row) * 65 + c] = acc2[mt][nt][r];
        }
  }
  __syncthreads();
  if (kh == 0) {
#pragma unroll
    for (int mt = 0; mt < 2; ++mt)
#pragma unroll
      for (int nt = 0; nt < 4; ++nt)
#pragma unroll
        for (int r = 0; r < 4; ++r) {
          int row = mt * 16 + lhi * 4 + r, c = nt * 16 + l15;
          acc2[mt][nt][r] += red[(rt * 32 + row) * 65 + c];
        }

    // ---- epilogue 1: bias+relu, d-sum -> out[ch 128..255]
#pragma unroll
    for (int mt = 0; mt < 2; ++mt) {
#pragma unroll
      for (int r = 0; r < 4; ++r) {
        int o = rt * 32 + mt * 16 + lhi * 4 + r;  // 0..127
        float bias = b1[o];
        float sb0 = 0.f, sb1 = 0.f;
#pragma unroll
        for (int nt = 0; nt < 4; ++nt) {
          float v = fmaxf(acc2[mt][nt][r] + bias, 0.f);
          v += __shfl_xor(v, 1); v += __shfl_xor(v, 2);
          v += __shfl_xor(v, 4); v += __shfl_xor(v, 8);
          if (nt < 2) sb0 += v; else sb1 += v;
        }
        if (l15 == 0) {
          out[(bb + 0) * 256 + 128 + o] = sb0;
          out[(bb + 1) * 256 + 128 + o] = sb1;
        }
      }
    }
  }
}

extern "C" void kernel_launch(void* const* d_in, const int* in_sizes, int n_in,
                              void* d_out, int out_size, void* d_ws, size_t ws_size,
                              hipStream_t stream) {
  const float* x  = (const float*)d_in[0];
  const float* w0 = (const float*)d_in[1];
  const float* b0 = (const float*)d_in[2];
  const float* w1 = (const float*)d_in[3];
  const float* b1 = (const float*)d_in[4];
  float* out = (float*)d_out;

  _Float16* w0c = (_Float16*)d_ws;             // 52*8192  f16 = 851968 B
  _Float16* w1c = w0c + K0P * 8192;            // 42*16384 f16 = 1376256 B

  prep_kernel<<<256, 256, 0, stream>>>(w0, w1, w0c, w1c);
  cin_kernel<<<NBLK, THREADS, 0, stream>>>(x, w0c, b0, w1c, b1, out);
}